// Round 1
// baseline (6611.025 us; speedup 1.0000x reference)
//
#include <hip/hip_runtime.h>
#include <hip/hip_bf16.h>

// Problem constants
#define BB   2
#define LL   2048
#define DD   2048
#define HH   16
#define KVH  4
#define HDD  128
#define RDD  64
#define MM   (BB*LL)   // 4096 rows of x

typedef __attribute__((ext_vector_type(4))) float f32x4;
typedef __attribute__((ext_vector_type(8))) short bf16x8;
typedef unsigned short u16;

// ---------------- f32 -> bf16 cast (vectorized) ----------------
__global__ __launch_bounds__(256) void cast_bf16_kernel(const float* __restrict__ in,
                                                        u16* __restrict__ out, int n4) {
  int i = blockIdx.x * 256 + threadIdx.x;
  if (i >= n4) return;
  float4 v = ((const float4*)in)[i];
  __hip_bfloat16 t0 = __float2bfloat16(v.x);
  __hip_bfloat16 t1 = __float2bfloat16(v.y);
  __hip_bfloat16 t2 = __float2bfloat16(v.z);
  __hip_bfloat16 t3 = __float2bfloat16(v.w);
  ushort4 o;
  o.x = *(const u16*)&t0; o.y = *(const u16*)&t1;
  o.z = *(const u16*)&t2; o.w = *(const u16*)&t3;
  ((ushort4*)out)[i] = o;
}

// ---------------- bf16 MFMA GEMM: C[M,N] = A[M,K] @ W[N,K]^T + bias ----------------
// One wave per 16x16 output tile. mfma_f32_16x16x32_bf16.
// A-frag: row = lane&15, k = (lane>>4)*8 + j  (8 contiguous bf16 = 16B load)
// B-frag: col = lane&15, k = (lane>>4)*8 + j  (B[k][n] = W[n][k])
// C/D   : col = lane&15, row = (lane>>4)*4 + reg   [verified layout]
__global__ __launch_bounds__(64) void gemm_bf16_nt(const u16* __restrict__ A,
                                                   const u16* __restrict__ W,
                                                   const float* __restrict__ bias,
                                                   float* __restrict__ C,
                                                   int M, int N, int K) {
  const int n0 = blockIdx.x * 16;
  const int m0 = blockIdx.y * 16;
  const int lane = threadIdx.x;
  const int r  = lane & 15;
  const int kq = (lane >> 4) * 8;
  const u16* ap = A + (size_t)(m0 + r) * K + kq;
  const u16* wp = W + (size_t)(n0 + r) * K + kq;
  f32x4 acc = {0.f, 0.f, 0.f, 0.f};
  for (int k = 0; k < K; k += 32) {
    bf16x8 a = *(const bf16x8*)(ap + k);
    bf16x8 b = *(const bf16x8*)(wp + k);
    acc = __builtin_amdgcn_mfma_f32_16x16x32_bf16(a, b, acc, 0, 0, 0);
  }
  const int col = lane & 15;
  const int rg  = (lane >> 4) * 4;
  const float bv = bias[n0 + col];
#pragma unroll
  for (int i = 0; i < 4; ++i)
    C[(size_t)(m0 + rg + i) * N + (n0 + col)] = acc[i] + bv;
}

// ---------------- RoPE on q (in place) + pre-scale by 1/sqrt(HD) ----------------
// thread j in [0,96) per (n,h): j<64 -> scale nope part; j in [64,96): rope pair (64+i, 96+i)
__global__ __launch_bounds__(256) void rope_q_kernel(float* __restrict__ qbuf,
                                                     const float* __restrict__ cosb,
                                                     const float* __restrict__ sinb) {
  const int idx = blockIdx.x * 256 + threadIdx.x;      // n*16*96 + h*96 + j
  const int j = idx % 96;
  const int t = idx / 96;
  const int h = t % HH;
  const int n = t / HH;
  const float scale = 0.08838834764831845f;            // 1/sqrt(128)
  float* qp = qbuf + (size_t)n * DD + h * HDD;
  if (j < 64) {
    qp[j] *= scale;
  } else {
    const int i = j - 64;                              // 0..31
    const float c1 = cosb[(size_t)n * RDD + i];
    const float s1 = sinb[(size_t)n * RDD + i];
    const float c2 = cosb[(size_t)n * RDD + i + 32];
    const float s2 = sinb[(size_t)n * RDD + i + 32];
    const float a  = qp[64 + i];
    const float b2 = qp[96 + i];
    qp[64 + i] = (a * c1 - b2 * s1) * scale;
    qp[96 + i] = (b2 * c2 + a * s2) * scale;
  }
}

// ---------------- RoPE on k_rope (in place, no scale) ----------------
__global__ __launch_bounds__(256) void rope_k_kernel(float* __restrict__ krbuf,
                                                     const float* __restrict__ cosb,
                                                     const float* __restrict__ sinb) {
  const int idx = blockIdx.x * 256 + threadIdx.x;      // n*32 + i
  const int i = idx & 31;
  const int n = idx >> 5;
  float* kp = krbuf + (size_t)n * RDD;
  const float c1 = cosb[(size_t)n * RDD + i];
  const float s1 = sinb[(size_t)n * RDD + i];
  const float c2 = cosb[(size_t)n * RDD + i + 32];
  const float s2 = sinb[(size_t)n * RDD + i + 32];
  const float a  = kp[i];
  const float b2 = kp[32 + i];
  kp[i]      = a * c1 - b2 * s1;
  kp[32 + i] = b2 * c2 + a * s2;
}

// ---------------- causal GQA attention, fp32, one wave per q row ----------------
// K row = [kv[c][0:64] | rope(k_rope)[0:64]], V row = kv[c][0:128]
// lanes span 64 keys; each lane computes the full 128-d dot for its key.
__global__ __launch_bounds__(256) void attn_kernel(const float* __restrict__ qbuf,
                                                   const float* __restrict__ kvbuf,
                                                   const float* __restrict__ krbuf,
                                                   u16* __restrict__ attn_bf) {
  const int bh = blockIdx.x;                 // b*16 + h
  const int b = bh >> 4, h = bh & 15;
  const int c = h >> 2;                      // kv head (G=4)
  const int wave = threadIdx.x >> 6, lane = threadIdx.x & 63;
  const int l = blockIdx.y * 4 + wave;       // q row within (b,h)
  __shared__ __align__(16) float qsh[4][128];
  __shared__ __align__(16) float psh[4][64];
  const size_t nrow = (size_t)(b * LL + l);
  {
    float2 q2 = *(const float2*)(qbuf + nrow * DD + h * HDD + lane * 2);
    qsh[wave][lane * 2]     = q2.x;
    qsh[wave][lane * 2 + 1] = q2.y;
  }
  float m = -__builtin_inff(), lsum = 0.f, acc0 = 0.f, acc1 = 0.f;
  const float* Kc = kvbuf + (size_t)(b * LL) * (KVH * HDD) + c * HDD;
  const float* Rc = krbuf + (size_t)(b * LL) * RDD;
  for (int s0 = 0; s0 <= l; s0 += 64) {
    const int srow = s0 + lane;
    const bool valid = (srow <= l);
    const int sc = valid ? srow : l;         // clamp (always in-bounds)
    const float* kp = Kc + (size_t)sc * (KVH * HDD);
    const float* rp = Rc + (size_t)sc * RDD;
    float s = 0.f;
#pragma unroll
    for (int d0 = 0; d0 < 64; d0 += 4) {
      float4 k4 = *(const float4*)(kp + d0);
      float4 q4 = *(const float4*)(&qsh[wave][d0]);
      s += k4.x * q4.x + k4.y * q4.y + k4.z * q4.z + k4.w * q4.w;
    }
#pragma unroll
    for (int d0 = 0; d0 < 64; d0 += 4) {
      float4 k4 = *(const float4*)(rp + d0);
      float4 q4 = *(const float4*)(&qsh[wave][64 + d0]);
      s += k4.x * q4.x + k4.y * q4.y + k4.z * q4.z + k4.w * q4.w;
    }
    if (!valid) s = -__builtin_inff();
    float smax = s;
#pragma unroll
    for (int off = 32; off > 0; off >>= 1) smax = fmaxf(smax, __shfl_xor(smax, off));
    const float mnew = fmaxf(m, smax);
    const float p  = __expf(s - mnew);       // masked lanes: exp(-inf)=0
    const float cf = __expf(m - mnew);       // first tile: exp(-inf)=0
    float psum = p;
#pragma unroll
    for (int off = 32; off > 0; off >>= 1) psum += __shfl_xor(psum, off);
    lsum = lsum * cf + psum;
    acc0 *= cf; acc1 *= cf;
    m = mnew;
    psh[wave][lane] = p;
    const float* vp = kvbuf + (size_t)(b * LL + s0) * (KVH * HDD) + c * HDD + lane * 2;
#pragma unroll 4
    for (int j = 0; j < 64; j += 4) {        // masked p are 0; rows s0+63 <= 2047 always
      float4 p4 = *(const float4*)(&psh[wave][j]);
      float2 v0 = *(const float2*)(vp + (size_t)(j + 0) * (KVH * HDD));
      float2 v1 = *(const float2*)(vp + (size_t)(j + 1) * (KVH * HDD));
      float2 v2 = *(const float2*)(vp + (size_t)(j + 2) * (KVH * HDD));
      float2 v3 = *(const float2*)(vp + (size_t)(j + 3) * (KVH * HDD));
      acc0 += p4.x * v0.x + p4.y * v1.x + p4.z * v2.x + p4.w * v3.x;
      acc1 += p4.x * v0.y + p4.y * v1.y + p4.z * v2.y + p4.w * v3.y;
    }
  }
  const float inv = 1.f / lsum;
  __hip_bfloat16 o0 = __float2bfloat16(acc0 * inv);
  __hip_bfloat16 o1 = __float2bfloat16(acc1 * inv);
  ushort2 o; o.x = *(const u16*)&o0; o.y = *(const u16*)&o1;
  *((ushort2*)(attn_bf + nrow * DD + h * HDD + lane * 2)) = o;
}

extern "C" void kernel_launch(void* const* d_in, const int* in_sizes, int n_in,
                              void* d_out, int out_size, void* d_ws, size_t ws_size,
                              hipStream_t stream) {
  const float* x    = (const float*)d_in[0];
  const float* cosb = (const float*)d_in[1];
  const float* sinb = (const float*)d_in[2];
  const float* Wq   = (const float*)d_in[3];
  const float* bq   = (const float*)d_in[4];
  const float* Wkv  = (const float*)d_in[5];
  const float* bkv  = (const float*)d_in[6];
  const float* Wrk  = (const float*)d_in[7];
  const float* brk  = (const float*)d_in[8];
  const float* Wo   = (const float*)d_in[9];
  const float* bo   = (const float*)d_in[10];
  float* out = (float*)d_out;

  char* ws = (char*)d_ws;
  float* kvbuf = (float*)(ws);                    // 4096*512*4  = 8,388,608
  float* krbuf = (float*)(ws + 8388608);          // 4096*64*4   = 1,048,576
  float* qbuf  = (float*)(ws + 9437184);          // 4096*2048*4 = 33,554,432
  u16*   xb    = (u16*)(ws + 42991616);           // 4096*2048*2 = 16,777,216
  u16*   Wqb   = (u16*)(ws + 59768832);           // 8,388,608
  u16*   Wkvb  = (u16*)(ws + 68157440);           // 2,097,152
  u16*   Wrkb  = (u16*)(ws + 70254592);           // 262,144
  u16*   Wob   = (u16*)(ws + 70516736);           // 8,388,608 -> end 78,905,344
  u16*   attn_bf = xb;                            // xb is dead after the 3 input GEMMs

  // 1) casts to bf16
  cast_bf16_kernel<<<(MM * DD / 4) / 256, 256, 0, stream>>>(x, xb, MM * DD / 4);
  cast_bf16_kernel<<<(HH * HDD * DD / 4) / 256, 256, 0, stream>>>(Wq, Wqb, HH * HDD * DD / 4);
  cast_bf16_kernel<<<(KVH * HDD * DD / 4) / 256, 256, 0, stream>>>(Wkv, Wkvb, KVH * HDD * DD / 4);
  cast_bf16_kernel<<<(RDD * DD / 4) / 256, 256, 0, stream>>>(Wrk, Wrkb, RDD * DD / 4);
  cast_bf16_kernel<<<(DD * HH * HDD / 4) / 256, 256, 0, stream>>>(Wo, Wob, DD * HH * HDD / 4);

  // 2) input projections
  gemm_bf16_nt<<<dim3(DD / 16, MM / 16), 64, 0, stream>>>(xb, Wqb, bq, qbuf, MM, DD, DD);
  gemm_bf16_nt<<<dim3((KVH * HDD) / 16, MM / 16), 64, 0, stream>>>(xb, Wkvb, bkv, kvbuf, MM, KVH * HDD, DD);
  gemm_bf16_nt<<<dim3(RDD / 16, MM / 16), 64, 0, stream>>>(xb, Wrkb, brk, krbuf, MM, RDD, DD);

  // 3) RoPE (in place) + q pre-scale
  rope_q_kernel<<<(MM * HH * 96) / 256, 256, 0, stream>>>(qbuf, cosb, sinb);
  rope_k_kernel<<<(MM * 32) / 256, 256, 0, stream>>>(krbuf, cosb, sinb);

  // 4) attention -> bf16
  attn_kernel<<<dim3(BB * HH, LL / 4), 256, 0, stream>>>(qbuf, kvbuf, krbuf, attn_bf);

  // 5) output projection -> d_out (f32)
  gemm_bf16_nt<<<dim3(DD / 16, MM / 16), 64, 0, stream>>>(attn_bf, Wob, bo, out, MM, DD, DD);
}

// Round 3
// 1658.982 us; speedup vs baseline: 3.9850x; 3.9850x over previous
//
#include <hip/hip_runtime.h>
#include <hip/hip_bf16.h>

// Problem constants
#define BB   2
#define LL   2048
#define DD   2048
#define HH   16
#define KVH  4
#define HDD  128
#define RDD  64
#define MM   (BB*LL)   // 4096 rows of x

typedef __attribute__((ext_vector_type(4))) float f32x4;
typedef __attribute__((ext_vector_type(8))) short bf16x8;
typedef unsigned short u16;

static __device__ __forceinline__ u16 f2b(float f) {
  __hip_bfloat16 b = __float2bfloat16(f);
  return *(const u16*)&b;
}

// ---------------- f32 -> bf16 cast (vectorized) ----------------
__global__ __launch_bounds__(256) void cast_bf16_kernel(const float* __restrict__ in,
                                                        u16* __restrict__ out, int n4) {
  int i = blockIdx.x * 256 + threadIdx.x;
  if (i >= n4) return;
  float4 v = ((const float4*)in)[i];
  ushort4 o;
  o.x = f2b(v.x); o.y = f2b(v.y); o.z = f2b(v.z); o.w = f2b(v.w);
  ((ushort4*)out)[i] = o;
}

// ---------------- bf16 MFMA GEMM: C[M,N] = A[M,K] @ W[N,K]^T + bias ----------------
__global__ __launch_bounds__(64) void gemm_bf16_nt(const u16* __restrict__ A,
                                                   const u16* __restrict__ W,
                                                   const float* __restrict__ bias,
                                                   float* __restrict__ C,
                                                   int M, int N, int K) {
  const int n0 = blockIdx.x * 16;
  const int m0 = blockIdx.y * 16;
  const int lane = threadIdx.x;
  const int r  = lane & 15;
  const int kq = (lane >> 4) * 8;
  const u16* ap = A + (size_t)(m0 + r) * K + kq;
  const u16* wp = W + (size_t)(n0 + r) * K + kq;
  f32x4 acc = {0.f, 0.f, 0.f, 0.f};
  for (int k = 0; k < K; k += 32) {
    bf16x8 a = *(const bf16x8*)(ap + k);
    bf16x8 b = *(const bf16x8*)(wp + k);
    acc = __builtin_amdgcn_mfma_f32_16x16x32_bf16(a, b, acc, 0, 0, 0);
  }
  const int col = lane & 15;
  const int rg  = (lane >> 4) * 4;
  const float bv = bias[n0 + col];
#pragma unroll
  for (int i = 0; i < 4; ++i)
    C[(size_t)(m0 + rg + i) * N + (n0 + col)] = acc[i] + bv;
}

// ---------------- build Qb: rope + scale + bf16, head-major [b][h][l][128] ----------------
__global__ __launch_bounds__(256) void build_q_kernel(const float* __restrict__ qbuf,
                                                      const float* __restrict__ cosb,
                                                      const float* __restrict__ sinb,
                                                      u16* __restrict__ Qb) {
  const int idx = blockIdx.x * 256 + threadIdx.x;   // ((b*16+h)*2048+l)*128 + d
  const int d = idx & 127;
  const int t = idx >> 7;
  const int l = t & 2047;
  const int bh = t >> 11;
  const int h = bh & 15, b = bh >> 4;
  const int n = b * LL + l;
  const float qscale = 0.08838834764831845f;        // 1/sqrt(128)
  const float* qp = qbuf + (size_t)n * DD + h * HDD;
  float val;
  if (d < 64) {
    val = qp[d];
  } else {
    const int i = d - 64;
    const float cv = cosb[(size_t)n * RDD + i];
    const float sv = sinb[(size_t)n * RDD + i];
    val = (i < 32) ? (qp[d] * cv - qp[d + 32] * sv)
                   : (qp[d] * cv + qp[d - 32] * sv);
  }
  Qb[idx] = f2b(val * qscale);
}

// ---------------- build Kb: [kv_tied | roped k_rope] bf16, [b][c][s][128] ----------------
__global__ __launch_bounds__(256) void build_k_kernel(const float* __restrict__ kvbuf,
                                                      const float* __restrict__ krbuf,
                                                      const float* __restrict__ cosb,
                                                      const float* __restrict__ sinb,
                                                      u16* __restrict__ Kb) {
  const int idx = blockIdx.x * 256 + threadIdx.x;   // ((b*4+c)*2048+s)*128 + d
  const int d = idx & 127;
  const int t = idx >> 7;
  const int s = t & 2047;
  const int bc = t >> 11;
  const int b = bc >> 2, c = bc & 3;
  const int n = b * LL + s;
  float val;
  if (d < 64) {
    val = kvbuf[(size_t)n * (KVH * HDD) + c * HDD + d];
  } else {
    const int i = d - 64;
    const float cv = cosb[(size_t)n * RDD + i];
    const float sv = sinb[(size_t)n * RDD + i];
    const float* kr = krbuf + (size_t)n * RDD;
    val = (i < 32) ? (kr[i] * cv - kr[i + 32] * sv)
                   : (kr[i] * cv + kr[i - 32] * sv);
  }
  Kb[idx] = f2b(val);
}

// ---------------- build VT: transpose V to [b][c][d][s] bf16 ----------------
__global__ __launch_bounds__(256) void build_vt_kernel(const float* __restrict__ kvbuf,
                                                       u16* __restrict__ VT) {
  __shared__ float tile[32][33];
  const int bc = blockIdx.z;
  const int b = bc >> 2, c = bc & 3;
  const int s0 = blockIdx.x * 32, d0 = blockIdx.y * 32;
  const int tx = threadIdx.x & 31, ty = threadIdx.x >> 5;   // 32 x 8
#pragma unroll
  for (int k = 0; k < 4; ++k) {
    const int s = s0 + ty + k * 8;
    tile[ty + k * 8][tx] = kvbuf[(size_t)(b * LL + s) * (KVH * HDD) + c * HDD + d0 + tx];
  }
  __syncthreads();
#pragma unroll
  for (int k = 0; k < 4; ++k) {
    const int d = d0 + ty + k * 8;
    VT[(size_t)(bc * HDD + d) * LL + s0 + tx] = f2b(tile[tx][ty + k * 8]);
  }
}

// ---------------- MFMA flash attention ----------------
// grid (L/64, B*H), 256 threads. Wave w owns q rows [q_low, q_low+16).
__global__ __launch_bounds__(256) void attn_mfma(const u16* __restrict__ Qb,
                                                 const u16* __restrict__ Kb,
                                                 const u16* __restrict__ VTb,
                                                 u16* __restrict__ attn_bf) {
  const int bh = blockIdx.y;
  const int b = bh >> 4, h = bh & 15, c = h >> 2;
  const int w = threadIdx.x >> 6, lane = threadIdx.x & 63;
  const int q_low = blockIdx.x * 64 + w * 16;
  const int r = lane & 15, ko = (lane >> 4) * 8, rg = (lane >> 4) * 4;
  __shared__ u16 plds[4][16][72];                   // pad 64->72: 2-way banks (free)

  const u16* Qp = Qb + ((size_t)bh * LL + q_low) * HDD;
  bf16x8 qf[4];
#pragma unroll
  for (int ks = 0; ks < 4; ++ks)
    qf[ks] = *(const bf16x8*)(Qp + (size_t)r * HDD + ks * 32 + ko);

  const u16* Kp = Kb + (size_t)(b * KVH + c) * LL * HDD;
  const u16* Vp = VTb + (size_t)(b * KVH + c) * HDD * LL;

  float m_[4], l_[4];
  f32x4 o[8];
#pragma unroll
  for (int i = 0; i < 4; ++i) { m_[i] = -3.0e38f; l_[i] = 0.f; }
#pragma unroll
  for (int t = 0; t < 8; ++t) o[t] = (f32x4){0.f, 0.f, 0.f, 0.f};

  for (int s0 = 0; s0 <= q_low + 15; s0 += 64) {
    // ---- QK^T: 4 tiles of 16 keys, K=128 contraction ----
    f32x4 st[4];
#pragma unroll
    for (int t = 0; t < 4; ++t) {
      f32x4 acc = {0.f, 0.f, 0.f, 0.f};
      const u16* kp = Kp + (size_t)(s0 + t * 16 + r) * HDD + ko;
#pragma unroll
      for (int ks = 0; ks < 4; ++ks)
        acc = __builtin_amdgcn_mfma_f32_16x16x32_bf16(qf[ks], *(const bf16x8*)(kp + ks * 32), acc, 0, 0, 0);
      st[t] = acc;
    }
    // ---- causal mask (diagonal blocks only) ----
    if (s0 + 63 > q_low) {
#pragma unroll
      for (int t = 0; t < 4; ++t)
#pragma unroll
        for (int i = 0; i < 4; ++i)
          if (s0 + t * 16 + r > q_low + rg + i) st[t][i] = -3.0e38f;
    }
    // ---- online softmax (rows rg+i live in 16-lane groups) ----
    float mnew[4], cf[4], psum[4];
#pragma unroll
    for (int i = 0; i < 4; ++i) {
      float v = fmaxf(fmaxf(st[0][i], st[1][i]), fmaxf(st[2][i], st[3][i]));
      v = fmaxf(v, __shfl_xor(v, 1)); v = fmaxf(v, __shfl_xor(v, 2));
      v = fmaxf(v, __shfl_xor(v, 4)); v = fmaxf(v, __shfl_xor(v, 8));
      mnew[i] = fmaxf(m_[i], v);
      cf[i] = __expf(m_[i] - mnew[i]);
      psum[i] = 0.f;
    }
#pragma unroll
    for (int t = 0; t < 4; ++t)
#pragma unroll
      for (int i = 0; i < 4; ++i) {
        float p = __expf(st[t][i] - mnew[i]);
        psum[i] += p;
        plds[w][rg + i][t * 16 + r] = f2b(p);
      }
#pragma unroll
    for (int i = 0; i < 4; ++i) {
      float v = psum[i];
      v += __shfl_xor(v, 1); v += __shfl_xor(v, 2);
      v += __shfl_xor(v, 4); v += __shfl_xor(v, 8);
      l_[i] = l_[i] * cf[i] + v;
      m_[i] = mnew[i];
    }
#pragma unroll
    for (int t = 0; t < 8; ++t)
#pragma unroll
      for (int i = 0; i < 4; ++i) o[t][i] *= cf[i];
    // ---- PV: out(16q x 128d) += P(16x64) @ V(64x128), via VT rows ----
#pragma unroll
    for (int kb = 0; kb < 2; ++kb) {
      bf16x8 pa = *(const bf16x8*)&plds[w][r][kb * 32 + ko];
#pragma unroll
      for (int t = 0; t < 8; ++t) {
        const u16* vp = Vp + (size_t)(t * 16 + r) * LL + s0 + kb * 32 + ko;
        o[t] = __builtin_amdgcn_mfma_f32_16x16x32_bf16(pa, *(const bf16x8*)vp, o[t], 0, 0, 0);
      }
    }
  }
  float inv[4];
#pragma unroll
  for (int i = 0; i < 4; ++i) inv[i] = 1.f / l_[i];
  u16* op = attn_bf + (size_t)(b * LL + q_low + rg) * DD + h * HDD;
#pragma unroll
  for (int t = 0; t < 8; ++t)
#pragma unroll
    for (int i = 0; i < 4; ++i)
      op[(size_t)i * DD + t * 16 + r] = f2b(o[t][i] * inv[i]);
}

extern "C" void kernel_launch(void* const* d_in, const int* in_sizes, int n_in,
                              void* d_out, int out_size, void* d_ws, size_t ws_size,
                              hipStream_t stream) {
  const float* x    = (const float*)d_in[0];
  const float* cosb = (const float*)d_in[1];
  const float* sinb = (const float*)d_in[2];
  const float* Wq   = (const float*)d_in[3];
  const float* bq   = (const float*)d_in[4];
  const float* Wkv  = (const float*)d_in[5];
  const float* bkv  = (const float*)d_in[6];
  const float* Wrk  = (const float*)d_in[7];
  const float* brk  = (const float*)d_in[8];
  const float* Wo   = (const float*)d_in[9];
  const float* bo   = (const float*)d_in[10];
  float* out = (float*)d_out;

  // Workspace layout (total 78,905,344 B):
  //  [0, 8M)           kvbuf f32
  //  [8M, 9M)          krbuf f32
  //  [9M, 41M)         qbuf f32          -> attn_bf (bf16, 16MB) after build_q
  //  [41M, 57M)        xb bf16           -> Qb (bf16) after input GEMMs
  //  [57M, 65M)        Wob bf16
  //  [65M, 67M)        Wkvb bf16
  //  [67M, 67.25M)     Wrkb bf16
  //  [67.25M, 75.25M)  Wqb bf16          -> Kb (4MB) + VTb (4MB) after GEMMs
  char* ws = (char*)d_ws;
  float* kvbuf = (float*)(ws);
  float* krbuf = (float*)(ws + 8388608);
  float* qbuf  = (float*)(ws + 9437184);
  u16*   attn_bf = (u16*)(ws + 9437184);          // reuses qbuf (dead after build_q)
  u16*   xb    = (u16*)(ws + 42991616);
  u16*   Qb    = (u16*)(ws + 42991616);           // reuses xb (dead after GEMMs)
  u16*   Wob   = (u16*)(ws + 59768832);
  u16*   Wkvb  = (u16*)(ws + 68157440);
  u16*   Wrkb  = (u16*)(ws + 70254592);
  u16*   Wqb   = (u16*)(ws + 70516736);
  u16*   Kb    = (u16*)(ws + 70516736);           // reuses Wqb (dead after q GEMM)
  u16*   VTb   = (u16*)(ws + 74711040);

  // 1) casts to bf16
  cast_bf16_kernel<<<(MM * DD / 4) / 256, 256, 0, stream>>>(x, xb, MM * DD / 4);
  cast_bf16_kernel<<<(HH * HDD * DD / 4) / 256, 256, 0, stream>>>(Wq, Wqb, HH * HDD * DD / 4);
  cast_bf16_kernel<<<(KVH * HDD * DD / 4) / 256, 256, 0, stream>>>(Wkv, Wkvb, KVH * HDD * DD / 4);
  cast_bf16_kernel<<<(RDD * DD / 4) / 256, 256, 0, stream>>>(Wrk, Wrkb, RDD * DD / 4);
  cast_bf16_kernel<<<(DD * HH * HDD / 4) / 256, 256, 0, stream>>>(Wo, Wob, DD * HH * HDD / 4);

  // 2) input projections (f32 out)
  gemm_bf16_nt<<<dim3(DD / 16, MM / 16), 64, 0, stream>>>(xb, Wqb, bq, qbuf, MM, DD, DD);
  gemm_bf16_nt<<<dim3((KVH * HDD) / 16, MM / 16), 64, 0, stream>>>(xb, Wkvb, bkv, kvbuf, MM, KVH * HDD, DD);
  gemm_bf16_nt<<<dim3(RDD / 16, MM / 16), 64, 0, stream>>>(xb, Wrkb, brk, krbuf, MM, RDD, DD);

  // 3) build bf16 attention operands (rope folded in)
  build_k_kernel<<<(BB * KVH * LL * HDD) / 256, 256, 0, stream>>>(kvbuf, krbuf, cosb, sinb, Kb);
  build_vt_kernel<<<dim3(LL / 32, HDD / 32, BB * KVH), 256, 0, stream>>>(kvbuf, VTb);
  build_q_kernel<<<(MM * HH * HDD) / 256, 256, 0, stream>>>(qbuf, cosb, sinb, Qb);

  // 4) MFMA flash attention -> bf16
  attn_mfma<<<dim3(LL / 64, BB * HH), 256, 0, stream>>>(Qb, Kb, VTb, attn_bf);

  // 5) output projection -> d_out (f32)
  gemm_bf16_nt<<<dim3(DD / 16, MM / 16), 64, 0, stream>>>(attn_bf, Wob, bo, out, MM, DD, DD);
}

// Round 4
// 385.731 us; speedup vs baseline: 17.1389x; 4.3009x over previous
//
#include <hip/hip_runtime.h>
#include <hip/hip_bf16.h>

// Problem constants
#define BB   2
#define LL   2048
#define DD   2048
#define HH   16
#define KVH  4
#define HDD  128
#define RDD  64
#define MM   (BB*LL)   // 4096 rows of x

typedef __attribute__((ext_vector_type(4))) float f32x4;
typedef __attribute__((ext_vector_type(8))) short bf16x8;
typedef unsigned short u16;

static __device__ __forceinline__ u16 f2b(float f) {
  __hip_bfloat16 b = __float2bfloat16(f);
  return *(const u16*)&b;
}

// async global(16B/lane) -> LDS (wave-uniform base + lane*16)
static __device__ __forceinline__ void gload_lds16(const void* g, void* l) {
  __builtin_amdgcn_global_load_lds(
      (const __attribute__((address_space(1))) unsigned int*)g,
      (__attribute__((address_space(3))) unsigned int*)l, 16, 0, 0);
}

// ---------------- f32 -> bf16 cast (vectorized) ----------------
__global__ __launch_bounds__(256) void cast_bf16_kernel(const float* __restrict__ in,
                                                        u16* __restrict__ out, int n4) {
  int i = blockIdx.x * 256 + threadIdx.x;
  if (i >= n4) return;
  float4 v = ((const float4*)in)[i];
  ushort4 o;
  o.x = f2b(v.x); o.y = f2b(v.y); o.z = f2b(v.z); o.w = f2b(v.w);
  ((ushort4*)out)[i] = o;
}

// ---------------- small GEMM (kept for N=64): C[M,N] = A @ W^T + bias ----------------
__global__ __launch_bounds__(64) void gemm_bf16_nt(const u16* __restrict__ A,
                                                   const u16* __restrict__ W,
                                                   const float* __restrict__ bias,
                                                   float* __restrict__ C,
                                                   int M, int N, int K) {
  const int n0 = blockIdx.x * 16;
  const int m0 = blockIdx.y * 16;
  const int lane = threadIdx.x;
  const int r  = lane & 15;
  const int kq = (lane >> 4) * 8;
  const u16* ap = A + (size_t)(m0 + r) * K + kq;
  const u16* wp = W + (size_t)(n0 + r) * K + kq;
  f32x4 acc = {0.f, 0.f, 0.f, 0.f};
  for (int k = 0; k < K; k += 32) {
    bf16x8 a = *(const bf16x8*)(ap + k);
    bf16x8 b = *(const bf16x8*)(wp + k);
    acc = __builtin_amdgcn_mfma_f32_16x16x32_bf16(a, b, acc, 0, 0, 0);
  }
  const int col = lane & 15;
  const int rg  = (lane >> 4) * 4;
  const float bv = bias[n0 + col];
#pragma unroll
  for (int i = 0; i < 4; ++i)
    C[(size_t)(m0 + rg + i) * N + (n0 + col)] = acc[i] + bv;
}

// ---------------- m97-style 128x128 tile GEMM: C[M,N] = A[M,K] @ W[N,K]^T + bias ----
// 256 thr = 4 waves (2x2), each wave 64x64 (4x4 of 16x16 frags), BK=32,
// global_load_lds staging, 16 MFMA : 8 ds_read_b128 per wave per K-step.
__global__ __launch_bounds__(256) void gemm128(const u16* __restrict__ A,
                                               const u16* __restrict__ W,
                                               const float* __restrict__ bias,
                                               float* __restrict__ C,
                                               int M, int N, int K) {
  __shared__ u16 As[128 * 32];
  __shared__ u16 Bs[128 * 32];
  const int w = threadIdx.x >> 6, lane = threadIdx.x & 63;
  const int r = lane & 15, hi = lane >> 4, rg = hi * 4;
  const int wm = w >> 1, wn = w & 1;
  const int m0 = blockIdx.y * 128, n0 = blockIdx.x * 128;
  const int srow = w * 32 + (lane >> 2);   // staging row (i*16 added below)
  const int scb  = (lane & 3) * 16;        // staging col byte within 64B row
  f32x4 acc[4][4];
#pragma unroll
  for (int i = 0; i < 4; ++i)
#pragma unroll
    for (int j = 0; j < 4; ++j) acc[i][j] = (f32x4){0.f, 0.f, 0.f, 0.f};

  for (int k0 = 0; k0 < K; k0 += 32) {
#pragma unroll
    for (int i = 0; i < 2; ++i) {
      gload_lds16((const char*)(A + (size_t)(m0 + srow + i * 16) * K + k0) + scb,
                  (char*)As + (w * 2 + i) * 1024);
      gload_lds16((const char*)(W + (size_t)(n0 + srow + i * 16) * K + k0) + scb,
                  (char*)Bs + (w * 2 + i) * 1024);
    }
    __syncthreads();   // drains vmcnt(0) (compiler) -> tiles ready
    bf16x8 a[4], b[4];
#pragma unroll
    for (int i = 0; i < 4; ++i)
      a[i] = *(const bf16x8*)((const char*)As + (wm * 64 + i * 16 + r) * 64 + hi * 16);
#pragma unroll
    for (int j = 0; j < 4; ++j)
      b[j] = *(const bf16x8*)((const char*)Bs + (wn * 64 + j * 16 + r) * 64 + hi * 16);
#pragma unroll
    for (int i = 0; i < 4; ++i)
#pragma unroll
      for (int j = 0; j < 4; ++j)
        acc[i][j] = __builtin_amdgcn_mfma_f32_16x16x32_bf16(a[i], b[j], acc[i][j], 0, 0, 0);
    __syncthreads();
  }
#pragma unroll
  for (int j = 0; j < 4; ++j) {
    const float bv = bias[n0 + wn * 64 + j * 16 + r];
#pragma unroll
    for (int i = 0; i < 4; ++i)
#pragma unroll
      for (int ii = 0; ii < 4; ++ii)
        C[(size_t)(m0 + wm * 64 + i * 16 + rg + ii) * N + n0 + wn * 64 + j * 16 + r] =
            acc[i][j][ii] + bv;
  }
}

// ---------------- build Qb: rope + scale + bf16, head-major [b][h][l][128] ----------------
__global__ __launch_bounds__(256) void build_q_kernel(const float* __restrict__ qbuf,
                                                      const float* __restrict__ cosb,
                                                      const float* __restrict__ sinb,
                                                      u16* __restrict__ Qb) {
  const int idx = blockIdx.x * 256 + threadIdx.x;   // ((b*16+h)*2048+l)*128 + d
  const int d = idx & 127;
  const int t = idx >> 7;
  const int l = t & 2047;
  const int bh = t >> 11;
  const int h = bh & 15, b = bh >> 4;
  const int n = b * LL + l;
  const float qscale = 0.08838834764831845f;        // 1/sqrt(128)
  const float* qp = qbuf + (size_t)n * DD + h * HDD;
  float val;
  if (d < 64) {
    val = qp[d];
  } else {
    const int i = d - 64;
    const float cv = cosb[(size_t)n * RDD + i];
    const float sv = sinb[(size_t)n * RDD + i];
    val = (i < 32) ? (qp[d] * cv - qp[d + 32] * sv)
                   : (qp[d] * cv + qp[d - 32] * sv);
  }
  Qb[idx] = f2b(val * qscale);
}

// ---------------- build Kb: [kv_tied | roped k_rope] bf16, [b][c][s][128] ----------------
__global__ __launch_bounds__(256) void build_k_kernel(const float* __restrict__ kvbuf,
                                                      const float* __restrict__ krbuf,
                                                      const float* __restrict__ cosb,
                                                      const float* __restrict__ sinb,
                                                      u16* __restrict__ Kb) {
  const int idx = blockIdx.x * 256 + threadIdx.x;   // ((b*4+c)*2048+s)*128 + d
  const int d = idx & 127;
  const int t = idx >> 7;
  const int s = t & 2047;
  const int bc = t >> 11;
  const int b = bc >> 2, c = bc & 3;
  const int n = b * LL + s;
  float val;
  if (d < 64) {
    val = kvbuf[(size_t)n * (KVH * HDD) + c * HDD + d];
  } else {
    const int i = d - 64;
    const float cv = cosb[(size_t)n * RDD + i];
    const float sv = sinb[(size_t)n * RDD + i];
    const float* kr = krbuf + (size_t)n * RDD;
    val = (i < 32) ? (kr[i] * cv - kr[i + 32] * sv)
                   : (kr[i] * cv + kr[i - 32] * sv);
  }
  Kb[idx] = f2b(val);
}

// ---------------- build VT: transpose V to [b][c][d][s] bf16 ----------------
__global__ __launch_bounds__(256) void build_vt_kernel(const float* __restrict__ kvbuf,
                                                       u16* __restrict__ VT) {
  __shared__ float tile[32][33];
  const int bc = blockIdx.z;
  const int b = bc >> 2, c = bc & 3;
  const int s0 = blockIdx.x * 32, d0 = blockIdx.y * 32;
  const int tx = threadIdx.x & 31, ty = threadIdx.x >> 5;   // 32 x 8
#pragma unroll
  for (int k = 0; k < 4; ++k) {
    const int s = s0 + ty + k * 8;
    tile[ty + k * 8][tx] = kvbuf[(size_t)(b * LL + s) * (KVH * HDD) + c * HDD + d0 + tx];
  }
  __syncthreads();
#pragma unroll
  for (int k = 0; k < 4; ++k) {
    const int d = d0 + ty + k * 8;
    VT[(size_t)(bc * HDD + d) * LL + s0 + tx] = f2b(tile[tx][ty + k * 8]);
  }
}

// ---------------- stage one KV tile (KVB=32) into LDS, swizzled ----------------
// K tile: [32][128] bf16 (256B rows), swizzle byte ^= ((row&7)<<4)  (16B granular)
// VT tile: [128][32] bf16 (64B rows),  swizzle byte ^= ((row&3)<<4)
static __device__ __forceinline__ void stage_tile(const u16* Kp, const u16* Vp,
                                                  u16* ksbuf, u16* vsbuf,
                                                  int s0, int w, int lane) {
  const int hi = lane >> 4, r = lane & 15;
#pragma unroll
  for (int i = 0; i < 2; ++i) {
    const int krow = (w * 2 + i) * 4 + hi;
    const int kcb = (r * 16) ^ ((krow & 7) << 4);
    gload_lds16((const char*)Kp + (size_t)(s0 + krow) * 256 + kcb,
                (char*)ksbuf + (w * 2 + i) * 1024);
    const int vrow = (w * 2 + i) * 16 + (lane >> 2);
    const int vcb = ((lane & 3) * 16) ^ ((vrow & 3) << 4);
    gload_lds16((const char*)Vp + (size_t)vrow * (LL * 2) + (size_t)s0 * 2 + vcb,
                (char*)vsbuf + (w * 2 + i) * 1024);
  }
}

// ---------------- MFMA flash attention v2 ----------------
// 1-D grid of 512 blocks; block id -> (bh = id&31, strip = id>>5);
// qb mapped so strips s and s+8 are complementary (constant per-CU work).
// 4 waves x 32 q-rows = 128 q rows/block; KVB=32 double-buffered in LDS.
__global__ __launch_bounds__(256, 1) void attn_mfma2(const u16* __restrict__ Qb,
                                                     const u16* __restrict__ Kb,
                                                     const u16* __restrict__ VTb,
                                                     u16* __restrict__ attn_bf) {
  const int id = blockIdx.x;
  const int bh = id & 31;
  const int strip = id >> 5;
  const int qb = (strip < 8) ? (15 - strip) : (strip - 8);
  const int b = bh >> 4, h = bh & 15, c = h >> 2;
  const int w = threadIdx.x >> 6, lane = threadIdx.x & 63;
  const int r = lane & 15, hi = lane >> 4, ko = hi * 8, rg = hi * 4;
  const int q0 = qb * 128 + w * 32;

  __shared__ u16 Ks[2][32 * 128];
  __shared__ u16 Vs[2][128 * 32];
  __shared__ u16 Ps[4][32][40];

  const u16* Qp = Qb + (size_t)bh * LL * HDD;
  const u16* Kp = Kb + (size_t)(b * KVH + c) * LL * HDD;
  const u16* Vp = VTb + (size_t)(b * KVH + c) * HDD * LL;

  bf16x8 qf[2][4];
#pragma unroll
  for (int qs = 0; qs < 2; ++qs)
#pragma unroll
    for (int ks = 0; ks < 4; ++ks)
      qf[qs][ks] = *(const bf16x8*)(Qp + (size_t)(q0 + qs * 16 + r) * HDD + ks * 32 + ko);

  float m_[2][4], l_[2][4];
  f32x4 o[2][8];
#pragma unroll
  for (int qs = 0; qs < 2; ++qs)
#pragma unroll
    for (int i = 0; i < 4; ++i) { m_[qs][i] = -3.0e38f; l_[qs][i] = 0.f; }
#pragma unroll
  for (int qs = 0; qs < 2; ++qs)
#pragma unroll
    for (int t = 0; t < 8; ++t) o[qs][t] = (f32x4){0.f, 0.f, 0.f, 0.f};

  const int nt = 4 * qb + 4;   // KV tiles (block-uniform; trailing tiles fully masked per-wave)

  stage_tile(Kp, Vp, &Ks[0][0], &Vs[0][0], 0, w, lane);
  __syncthreads();
  int cur = 0;

  for (int t = 0; t < nt; ++t) {
    const int s0 = t * 32;
    if (t + 1 < nt)
      stage_tile(Kp, Vp, &Ks[cur ^ 1][0], &Vs[cur ^ 1][0], s0 + 32, w, lane);

    const char* Kl = (const char*)&Ks[cur][0];
    const char* Vl = (const char*)&Vs[cur][0];

    // ---- QK^T: 2 key-subtiles x K=128 ----
    f32x4 st[2][2];
#pragma unroll
    for (int qs = 0; qs < 2; ++qs)
#pragma unroll
      for (int tt = 0; tt < 2; ++tt) st[qs][tt] = (f32x4){0.f, 0.f, 0.f, 0.f};
#pragma unroll
    for (int tt = 0; tt < 2; ++tt) {
      const int krow = tt * 16 + r;
      bf16x8 kf[4];
#pragma unroll
      for (int ks = 0; ks < 4; ++ks) {
        const int cb = (ks * 64 + hi * 16) ^ ((krow & 7) << 4);
        kf[ks] = *(const bf16x8*)(Kl + krow * 256 + cb);
      }
#pragma unroll
      for (int qs = 0; qs < 2; ++qs)
#pragma unroll
        for (int ks = 0; ks < 4; ++ks)
          st[qs][tt] = __builtin_amdgcn_mfma_f32_16x16x32_bf16(qf[qs][ks], kf[ks], st[qs][tt], 0, 0, 0);
    }

    // ---- causal mask (diagonal & beyond) ----
    if (s0 + 31 > q0) {
#pragma unroll
      for (int qs = 0; qs < 2; ++qs)
#pragma unroll
        for (int tt = 0; tt < 2; ++tt)
#pragma unroll
          for (int i = 0; i < 4; ++i)
            if (s0 + tt * 16 + r > q0 + qs * 16 + rg + i) st[qs][tt][i] = -3.0e38f;
    }

    // ---- online softmax (rows rg+i live in 16-lane groups) ----
    float cf[2][4];
#pragma unroll
    for (int qs = 0; qs < 2; ++qs)
#pragma unroll
      for (int i = 0; i < 4; ++i) {
        float v = fmaxf(st[qs][0][i], st[qs][1][i]);
        v = fmaxf(v, __shfl_xor(v, 1)); v = fmaxf(v, __shfl_xor(v, 2));
        v = fmaxf(v, __shfl_xor(v, 4)); v = fmaxf(v, __shfl_xor(v, 8));
        const float mn = fmaxf(m_[qs][i], v);
        cf[qs][i] = __expf(m_[qs][i] - mn);
        float ps = 0.f;
#pragma unroll
        for (int tt = 0; tt < 2; ++tt) {
          float p = __expf(st[qs][tt][i] - mn);
          ps += p;
          Ps[w][qs * 16 + rg + i][tt * 16 + r] = f2b(p);
        }
        ps += __shfl_xor(ps, 1); ps += __shfl_xor(ps, 2);
        ps += __shfl_xor(ps, 4); ps += __shfl_xor(ps, 8);
        l_[qs][i] = l_[qs][i] * cf[qs][i] + ps;
        m_[qs][i] = mn;
      }
#pragma unroll
    for (int qs = 0; qs < 2; ++qs)
#pragma unroll
      for (int tt = 0; tt < 8; ++tt)
#pragma unroll
        for (int i = 0; i < 4; ++i) o[qs][tt][i] *= cf[qs][i];

    // ---- PV: out(32q x 128d) += P(32x32) @ V(32x128) via swizzled VT tile ----
    bf16x8 pa[2];
#pragma unroll
    for (int qs = 0; qs < 2; ++qs)
      pa[qs] = *(const bf16x8*)&Ps[w][qs * 16 + r][ko];
#pragma unroll
    for (int tt = 0; tt < 8; ++tt) {
      const int vrow = tt * 16 + r;
      const int cb = (hi * 16) ^ ((vrow & 3) << 4);
      bf16x8 vf = *(const bf16x8*)(Vl + vrow * 64 + cb);
#pragma unroll
      for (int qs = 0; qs < 2; ++qs)
        o[qs][tt] = __builtin_amdgcn_mfma_f32_16x16x32_bf16(pa[qs], vf, o[qs][tt], 0, 0, 0);
    }

    __syncthreads();   // waves done reading cur; staged loads (vmcnt) drained
    cur ^= 1;
  }

  // ---- epilogue ----
#pragma unroll
  for (int qs = 0; qs < 2; ++qs) {
    float inv[4];
#pragma unroll
    for (int i = 0; i < 4; ++i) inv[i] = 1.f / l_[qs][i];
    u16* op = attn_bf + (size_t)(b * LL + q0 + qs * 16 + rg) * DD + h * HDD;
#pragma unroll
    for (int tt = 0; tt < 8; ++tt)
#pragma unroll
      for (int i = 0; i < 4; ++i)
        op[(size_t)i * DD + tt * 16 + r] = f2b(o[qs][tt][i] * inv[i]);
  }
}

extern "C" void kernel_launch(void* const* d_in, const int* in_sizes, int n_in,
                              void* d_out, int out_size, void* d_ws, size_t ws_size,
                              hipStream_t stream) {
  const float* x    = (const float*)d_in[0];
  const float* cosb = (const float*)d_in[1];
  const float* sinb = (const float*)d_in[2];
  const float* Wq   = (const float*)d_in[3];
  const float* bq   = (const float*)d_in[4];
  const float* Wkv  = (const float*)d_in[5];
  const float* bkv  = (const float*)d_in[6];
  const float* Wrk  = (const float*)d_in[7];
  const float* brk  = (const float*)d_in[8];
  const float* Wo   = (const float*)d_in[9];
  const float* bo   = (const float*)d_in[10];
  float* out = (float*)d_out;

  // Workspace layout (78,905,344 B total):
  //  [0, 8M)           kvbuf f32
  //  [8M, 9M)          krbuf f32
  //  [9M, 41M)         qbuf f32          -> attn_bf (bf16) after build_q
  //  [41M, 57M)        xb bf16           -> Qb (bf16) after input GEMMs
  //  [57M, 65M)        Wob bf16
  //  [65M, 67M)        Wkvb bf16
  //  [67M, 67.25M)     Wrkb bf16
  //  [67.25M, 75.25M)  Wqb bf16          -> Kb (4MB) + VTb (4MB) after q GEMM
  char* ws = (char*)d_ws;
  float* kvbuf = (float*)(ws);
  float* krbuf = (float*)(ws + 8388608);
  float* qbuf  = (float*)(ws + 9437184);
  u16*   attn_bf = (u16*)(ws + 9437184);
  u16*   xb    = (u16*)(ws + 42991616);
  u16*   Qb    = (u16*)(ws + 42991616);
  u16*   Wob   = (u16*)(ws + 59768832);
  u16*   Wkvb  = (u16*)(ws + 68157440);
  u16*   Wrkb  = (u16*)(ws + 70254592);
  u16*   Wqb   = (u16*)(ws + 70516736);
  u16*   Kb    = (u16*)(ws + 70516736);
  u16*   VTb   = (u16*)(ws + 74711040);

  // 1) casts to bf16
  cast_bf16_kernel<<<(MM * DD / 4) / 256, 256, 0, stream>>>(x, xb, MM * DD / 4);
  cast_bf16_kernel<<<(HH * HDD * DD / 4) / 256, 256, 0, stream>>>(Wq, Wqb, HH * HDD * DD / 4);
  cast_bf16_kernel<<<(KVH * HDD * DD / 4) / 256, 256, 0, stream>>>(Wkv, Wkvb, KVH * HDD * DD / 4);
  cast_bf16_kernel<<<(RDD * DD / 4) / 256, 256, 0, stream>>>(Wrk, Wrkb, RDD * DD / 4);
  cast_bf16_kernel<<<(DD * HH * HDD / 4) / 256, 256, 0, stream>>>(Wo, Wob, DD * HH * HDD / 4);

  // 2) input projections (f32 out)
  gemm128<<<dim3(DD / 128, MM / 128), 256, 0, stream>>>(xb, Wqb, bq, qbuf, MM, DD, DD);
  gemm128<<<dim3((KVH * HDD) / 128, MM / 128), 256, 0, stream>>>(xb, Wkvb, bkv, kvbuf, MM, KVH * HDD, DD);
  gemm_bf16_nt<<<dim3(RDD / 16, MM / 16), 64, 0, stream>>>(xb, Wrkb, brk, krbuf, MM, RDD, DD);

  // 3) build bf16 attention operands (rope folded in)
  build_k_kernel<<<(BB * KVH * LL * HDD) / 256, 256, 0, stream>>>(kvbuf, krbuf, cosb, sinb, Kb);
  build_vt_kernel<<<dim3(LL / 32, HDD / 32, BB * KVH), 256, 0, stream>>>(kvbuf, VTb);
  build_q_kernel<<<(MM * HH * HDD) / 256, 256, 0, stream>>>(qbuf, cosb, sinb, Qb);

  // 4) MFMA flash attention v2 -> bf16
  attn_mfma2<<<dim3(512), 256, 0, stream>>>(Qb, Kb, VTb, attn_bf);

  // 5) output projection -> d_out (f32)
  gemm128<<<dim3(DD / 128, MM / 128), 256, 0, stream>>>(attn_bf, Wob, bo, out, MM, DD, DD);
}

// Round 5
// 325.583 us; speedup vs baseline: 20.3052x; 1.1847x over previous
//
#include <hip/hip_runtime.h>
#include <hip/hip_bf16.h>

// Problem constants
#define BB   2
#define LL   2048
#define DD   2048
#define HH   16
#define KVH  4
#define HDD  128
#define RDD  64
#define MM   (BB*LL)   // 4096 rows of x

typedef __attribute__((ext_vector_type(4))) float f32x4;
typedef __attribute__((ext_vector_type(8))) short bf16x8;
typedef unsigned short u16;

static __device__ __forceinline__ u16 f2b(float f) {
  __hip_bfloat16 b = __float2bfloat16(f);
  return *(const u16*)&b;
}

// async global(16B/lane) -> LDS (wave-uniform base + lane*16)
static __device__ __forceinline__ void gload_lds16(const void* g, void* l) {
  __builtin_amdgcn_global_load_lds(
      (const __attribute__((address_space(1))) unsigned int*)g,
      (__attribute__((address_space(3))) unsigned int*)l, 16, 0, 0);
}

// ---------------- f32 -> bf16 cast (vectorized) ----------------
__global__ __launch_bounds__(256) void cast_bf16_kernel(const float* __restrict__ in,
                                                        u16* __restrict__ out, int n4) {
  int i = blockIdx.x * 256 + threadIdx.x;
  if (i >= n4) return;
  float4 v = ((const float4*)in)[i];
  ushort4 o;
  o.x = f2b(v.x); o.y = f2b(v.y); o.z = f2b(v.z); o.w = f2b(v.w);
  ((ushort4*)out)[i] = o;
}

// ---------------- small GEMM (kept for N=64): C[M,N] = A @ W^T + bias ----------------
__global__ __launch_bounds__(64) void gemm_bf16_nt(const u16* __restrict__ A,
                                                   const u16* __restrict__ W,
                                                   const float* __restrict__ bias,
                                                   float* __restrict__ C,
                                                   int M, int N, int K) {
  const int n0 = blockIdx.x * 16;
  const int m0 = blockIdx.y * 16;
  const int lane = threadIdx.x;
  const int r  = lane & 15;
  const int kq = (lane >> 4) * 8;
  const u16* ap = A + (size_t)(m0 + r) * K + kq;
  const u16* wp = W + (size_t)(n0 + r) * K + kq;
  f32x4 acc = {0.f, 0.f, 0.f, 0.f};
  for (int k = 0; k < K; k += 32) {
    bf16x8 a = *(const bf16x8*)(ap + k);
    bf16x8 b = *(const bf16x8*)(wp + k);
    acc = __builtin_amdgcn_mfma_f32_16x16x32_bf16(a, b, acc, 0, 0, 0);
  }
  const int col = lane & 15;
  const int rg  = (lane >> 4) * 4;
  const float bv = bias[n0 + col];
#pragma unroll
  for (int i = 0; i < 4; ++i)
    C[(size_t)(m0 + rg + i) * N + (n0 + col)] = acc[i] + bv;
}

// ---------------- m97-style 128x128 tile GEMM ----
__global__ __launch_bounds__(256) void gemm128(const u16* __restrict__ A,
                                               const u16* __restrict__ W,
                                               const float* __restrict__ bias,
                                               float* __restrict__ C,
                                               int M, int N, int K) {
  __shared__ u16 As[128 * 32];
  __shared__ u16 Bs[128 * 32];
  const int w = threadIdx.x >> 6, lane = threadIdx.x & 63;
  const int r = lane & 15, hi = lane >> 4, rg = hi * 4;
  const int wm = w >> 1, wn = w & 1;
  const int m0 = blockIdx.y * 128, n0 = blockIdx.x * 128;
  const int srow = w * 32 + (lane >> 2);
  const int scb  = (lane & 3) * 16;
  f32x4 acc[4][4];
#pragma unroll
  for (int i = 0; i < 4; ++i)
#pragma unroll
    for (int j = 0; j < 4; ++j) acc[i][j] = (f32x4){0.f, 0.f, 0.f, 0.f};

  for (int k0 = 0; k0 < K; k0 += 32) {
#pragma unroll
    for (int i = 0; i < 2; ++i) {
      gload_lds16((const char*)(A + (size_t)(m0 + srow + i * 16) * K + k0) + scb,
                  (char*)As + (w * 2 + i) * 1024);
      gload_lds16((const char*)(W + (size_t)(n0 + srow + i * 16) * K + k0) + scb,
                  (char*)Bs + (w * 2 + i) * 1024);
    }
    __syncthreads();
    bf16x8 a[4], b[4];
#pragma unroll
    for (int i = 0; i < 4; ++i)
      a[i] = *(const bf16x8*)((const char*)As + (wm * 64 + i * 16 + r) * 64 + hi * 16);
#pragma unroll
    for (int j = 0; j < 4; ++j)
      b[j] = *(const bf16x8*)((const char*)Bs + (wn * 64 + j * 16 + r) * 64 + hi * 16);
#pragma unroll
    for (int i = 0; i < 4; ++i)
#pragma unroll
      for (int j = 0; j < 4; ++j)
        acc[i][j] = __builtin_amdgcn_mfma_f32_16x16x32_bf16(a[i], b[j], acc[i][j], 0, 0, 0);
    __syncthreads();
  }
#pragma unroll
  for (int j = 0; j < 4; ++j) {
    const float bv = bias[n0 + wn * 64 + j * 16 + r];
#pragma unroll
    for (int i = 0; i < 4; ++i)
#pragma unroll
      for (int ii = 0; ii < 4; ++ii)
        C[(size_t)(m0 + wm * 64 + i * 16 + rg + ii) * N + n0 + wn * 64 + j * 16 + r] =
            acc[i][j][ii] + bv;
  }
}

// ---------------- build Qb: rope + scale + bf16, head-major [b][h][l][128] ----------------
__global__ __launch_bounds__(256) void build_q_kernel(const float* __restrict__ qbuf,
                                                      const float* __restrict__ cosb,
                                                      const float* __restrict__ sinb,
                                                      u16* __restrict__ Qb) {
  const int idx = blockIdx.x * 256 + threadIdx.x;
  const int d = idx & 127;
  const int t = idx >> 7;
  const int l = t & 2047;
  const int bh = t >> 11;
  const int h = bh & 15, b = bh >> 4;
  const int n = b * LL + l;
  const float qscale = 0.08838834764831845f;
  const float* qp = qbuf + (size_t)n * DD + h * HDD;
  float val;
  if (d < 64) {
    val = qp[d];
  } else {
    const int i = d - 64;
    const float cv = cosb[(size_t)n * RDD + i];
    const float sv = sinb[(size_t)n * RDD + i];
    val = (i < 32) ? (qp[d] * cv - qp[d + 32] * sv)
                   : (qp[d] * cv + qp[d - 32] * sv);
  }
  Qb[idx] = f2b(val * qscale);
}

// ---------------- build Kb: [kv_tied | roped k_rope] bf16, [b][c][s][128] ----------------
__global__ __launch_bounds__(256) void build_k_kernel(const float* __restrict__ kvbuf,
                                                      const float* __restrict__ krbuf,
                                                      const float* __restrict__ cosb,
                                                      const float* __restrict__ sinb,
                                                      u16* __restrict__ Kb) {
  const int idx = blockIdx.x * 256 + threadIdx.x;
  const int d = idx & 127;
  const int t = idx >> 7;
  const int s = t & 2047;
  const int bc = t >> 11;
  const int b = bc >> 2, c = bc & 3;
  const int n = b * LL + s;
  float val;
  if (d < 64) {
    val = kvbuf[(size_t)n * (KVH * HDD) + c * HDD + d];
  } else {
    const int i = d - 64;
    const float cv = cosb[(size_t)n * RDD + i];
    const float sv = sinb[(size_t)n * RDD + i];
    const float* kr = krbuf + (size_t)n * RDD;
    val = (i < 32) ? (kr[i] * cv - kr[i + 32] * sv)
                   : (kr[i] * cv + kr[i - 32] * sv);
  }
  Kb[idx] = f2b(val);
}

// ---------------- build VT: transpose V to [b][c][d][s] bf16 ----------------
__global__ __launch_bounds__(256) void build_vt_kernel(const float* __restrict__ kvbuf,
                                                       u16* __restrict__ VT) {
  __shared__ float tile[32][33];
  const int bc = blockIdx.z;
  const int b = bc >> 2, c = bc & 3;
  const int s0 = blockIdx.x * 32, d0 = blockIdx.y * 32;
  const int tx = threadIdx.x & 31, ty = threadIdx.x >> 5;
#pragma unroll
  for (int k = 0; k < 4; ++k) {
    const int s = s0 + ty + k * 8;
    tile[ty + k * 8][tx] = kvbuf[(size_t)(b * LL + s) * (KVH * HDD) + c * HDD + d0 + tx];
  }
  __syncthreads();
#pragma unroll
  for (int k = 0; k < 4; ++k) {
    const int d = d0 + ty + k * 8;
    VT[(size_t)(bc * HDD + d) * LL + s0 + tx] = f2b(tile[tx][ty + k * 8]);
  }
}

// ---------------- stage one KV tile (KVB=32) into LDS, swizzled ----------------
static __device__ __forceinline__ void stage_tile(const u16* Kp, const u16* Vp,
                                                  u16* ksbuf, u16* vsbuf,
                                                  int s0, int w, int lane) {
  const int hi = lane >> 4, r = lane & 15;
#pragma unroll
  for (int i = 0; i < 2; ++i) {
    const int krow = (w * 2 + i) * 4 + hi;
    const int kcb = (r * 16) ^ ((krow & 7) << 4);
    gload_lds16((const char*)Kp + (size_t)(s0 + krow) * 256 + kcb,
                (char*)ksbuf + (w * 2 + i) * 1024);
    const int vrow = (w * 2 + i) * 16 + (lane >> 2);
    const int vcb = ((lane & 3) * 16) ^ ((vrow & 3) << 4);
    gload_lds16((const char*)Vp + (size_t)vrow * (LL * 2) + (size_t)s0 * 2 + vcb,
                (char*)vsbuf + (w * 2 + i) * 1024);
  }
}

// ---------------- MFMA flash attention v3: swapped QK^T, in-lane softmax ----------------
// grid 512 blocks; 4 waves x 32 q-rows; KVB=32 double-buffered.
// S^T = mfma(K,Q): col=query(lane&15), row=key(4*hi+i) -> softmax is in-lane + 2 shuffles.
__global__ __launch_bounds__(256, 1) void attn_mfma3(const u16* __restrict__ Qb,
                                                     const u16* __restrict__ Kb,
                                                     const u16* __restrict__ VTb,
                                                     u16* __restrict__ attn_bf) {
  const int id = blockIdx.x;
  const int bh = id & 31;
  const int strip = id >> 5;
  const int qb = (strip < 8) ? (15 - strip) : (strip - 8);
  const int b = bh >> 4, h = bh & 15, c = h >> 2;
  const int w = threadIdx.x >> 6, lane = threadIdx.x & 63;
  const int r = lane & 15, hi = lane >> 4, rg = hi * 4;
  const int q0 = qb * 128 + w * 32;

  __shared__ u16 Ks[2][32 * 128];
  __shared__ u16 Vs[2][128 * 32];
  __shared__ __align__(16) u16 Ps[4][32][40];   // [q][k] bf16, stride 80B

  const u16* Qp = Qb + (size_t)bh * LL * HDD;
  const u16* Kp = Kb + (size_t)(b * KVH + c) * LL * HDD;
  const u16* Vp = VTb + (size_t)(b * KVH + c) * HDD * LL;

  bf16x8 qf[2][4];
#pragma unroll
  for (int qs = 0; qs < 2; ++qs)
#pragma unroll
    for (int ks = 0; ks < 4; ++ks)
      qf[qs][ks] = *(const bf16x8*)(Qp + (size_t)(q0 + qs * 16 + r) * HDD + ks * 32 + hi * 8);

  float m_[2] = {-3.0e38f, -3.0e38f}, l_[2] = {0.f, 0.f};
  f32x4 o[2][8];
#pragma unroll
  for (int qs = 0; qs < 2; ++qs)
#pragma unroll
    for (int t = 0; t < 8; ++t) o[qs][t] = (f32x4){0.f, 0.f, 0.f, 0.f};

  const int nt = 4 * qb + 4;

  stage_tile(Kp, Vp, &Ks[0][0], &Vs[0][0], 0, w, lane);
  __syncthreads();
  int cur = 0;

  for (int t = 0; t < nt; ++t) {
    const int s0 = t * 32;
    if (t + 1 < nt)
      stage_tile(Kp, Vp, &Ks[cur ^ 1][0], &Vs[cur ^ 1][0], s0 + 32, w, lane);

    const char* Kl = (const char*)&Ks[cur][0];
    const char* Vl = (const char*)&Vs[cur][0];

    // ---- swapped QK^T: st[qs][tt] col=query r, rows keys tt*16+4hi+i ----
    f32x4 st[2][2];
#pragma unroll
    for (int qs = 0; qs < 2; ++qs)
#pragma unroll
      for (int tt = 0; tt < 2; ++tt) st[qs][tt] = (f32x4){0.f, 0.f, 0.f, 0.f};
#pragma unroll
    for (int tt = 0; tt < 2; ++tt) {
      const int krow = tt * 16 + r;
      bf16x8 kf[4];
#pragma unroll
      for (int ks = 0; ks < 4; ++ks) {
        const int cb = (ks * 64 + hi * 16) ^ ((krow & 7) << 4);
        kf[ks] = *(const bf16x8*)(Kl + krow * 256 + cb);
      }
#pragma unroll
      for (int qs = 0; qs < 2; ++qs)
#pragma unroll
        for (int ks = 0; ks < 4; ++ks)
          st[qs][tt] = __builtin_amdgcn_mfma_f32_16x16x32_bf16(kf[ks], qf[qs][ks], st[qs][tt], 0, 0, 0);
    }

    // ---- causal mask: key s0+tt*16+4hi+i vs query q0+qs*16+r ----
    if (s0 + 31 > q0) {
#pragma unroll
      for (int qs = 0; qs < 2; ++qs)
#pragma unroll
        for (int tt = 0; tt < 2; ++tt)
#pragma unroll
          for (int i = 0; i < 4; ++i)
            if (s0 + tt * 16 + rg + i > q0 + qs * 16 + r) st[qs][tt][i] = -3.0e38f;
    }

    // ---- in-lane max + 2 shuffles ----
    float vmax[2];
#pragma unroll
    for (int qs = 0; qs < 2; ++qs) {
      float v = fmaxf(fmaxf(fmaxf(st[qs][0][0], st[qs][0][1]), fmaxf(st[qs][0][2], st[qs][0][3])),
                      fmaxf(fmaxf(st[qs][1][0], st[qs][1][1]), fmaxf(st[qs][1][2], st[qs][1][3])));
      v = fmaxf(v, __shfl_xor(v, 16));
      v = fmaxf(v, __shfl_xor(v, 32));
      vmax[qs] = v;
    }
    // ---- defer-max: rescale only when max grew past threshold ----
    const float grow = fmaxf(vmax[0] - m_[0], vmax[1] - m_[1]);
    if (!__all(grow <= 8.0f)) {
#pragma unroll
      for (int qs = 0; qs < 2; ++qs) {
        const float mn = fmaxf(m_[qs], vmax[qs]);
        const float cf = __expf(m_[qs] - mn);
        l_[qs] *= cf;
        m_[qs] = mn;
#pragma unroll
        for (int tt = 0; tt < 8; ++tt)
#pragma unroll
          for (int i = 0; i < 4; ++i) o[qs][tt][i] *= cf;
      }
    }
    // ---- exp, sum (in-lane + 2 shfl), pack P as 8B LDS stores ----
#pragma unroll
    for (int qs = 0; qs < 2; ++qs) {
      float ps = 0.f;
#pragma unroll
      for (int tt = 0; tt < 2; ++tt) {
        const float e0 = __expf(st[qs][tt][0] - m_[qs]);
        const float e1 = __expf(st[qs][tt][1] - m_[qs]);
        const float e2 = __expf(st[qs][tt][2] - m_[qs]);
        const float e3 = __expf(st[qs][tt][3] - m_[qs]);
        ps += (e0 + e1) + (e2 + e3);
        uint2 pw;
        pw.x = (unsigned)f2b(e0) | ((unsigned)f2b(e1) << 16);
        pw.y = (unsigned)f2b(e2) | ((unsigned)f2b(e3) << 16);
        *(uint2*)&Ps[w][qs * 16 + r][tt * 16 + rg] = pw;
      }
      ps += __shfl_xor(ps, 16);
      ps += __shfl_xor(ps, 32);
      l_[qs] += ps;
    }

    // ---- PV: O[q][d] += P(32x32) @ V(32x128) ----
    bf16x8 pa[2];
#pragma unroll
    for (int qs = 0; qs < 2; ++qs)
      pa[qs] = *(const bf16x8*)&Ps[w][qs * 16 + r][hi * 8];
#pragma unroll
    for (int tt = 0; tt < 8; ++tt) {
      const int vrow = tt * 16 + r;
      const int cb = (hi * 16) ^ ((vrow & 3) << 4);
      bf16x8 vf = *(const bf16x8*)(Vl + vrow * 64 + cb);
#pragma unroll
      for (int qs = 0; qs < 2; ++qs)
        o[qs][tt] = __builtin_amdgcn_mfma_f32_16x16x32_bf16(pa[qs], vf, o[qs][tt], 0, 0, 0);
    }

    __syncthreads();
    cur ^= 1;
  }

  // ---- epilogue: l_ lives at query=r lanes; o rows are query=rg+i -> shuffle ----
#pragma unroll
  for (int qs = 0; qs < 2; ++qs) {
    const float il = 1.f / l_[qs];
    float inv[4];
#pragma unroll
    for (int i = 0; i < 4; ++i)
      inv[i] = __shfl(il, (lane & 48) + rg + i);
    u16* op = attn_bf + (size_t)(b * LL + q0 + qs * 16 + rg) * DD + h * HDD;
#pragma unroll
    for (int tt = 0; tt < 8; ++tt)
#pragma unroll
      for (int i = 0; i < 4; ++i)
        op[(size_t)i * DD + tt * 16 + r] = f2b(o[qs][tt][i] * inv[i]);
  }
}

extern "C" void kernel_launch(void* const* d_in, const int* in_sizes, int n_in,
                              void* d_out, int out_size, void* d_ws, size_t ws_size,
                              hipStream_t stream) {
  const float* x    = (const float*)d_in[0];
  const float* cosb = (const float*)d_in[1];
  const float* sinb = (const float*)d_in[2];
  const float* Wq   = (const float*)d_in[3];
  const float* bq   = (const float*)d_in[4];
  const float* Wkv  = (const float*)d_in[5];
  const float* bkv  = (const float*)d_in[6];
  const float* Wrk  = (const float*)d_in[7];
  const float* brk  = (const float*)d_in[8];
  const float* Wo   = (const float*)d_in[9];
  const float* bo   = (const float*)d_in[10];
  float* out = (float*)d_out;

  char* ws = (char*)d_ws;
  float* kvbuf = (float*)(ws);
  float* krbuf = (float*)(ws + 8388608);
  float* qbuf  = (float*)(ws + 9437184);
  u16*   attn_bf = (u16*)(ws + 9437184);
  u16*   xb    = (u16*)(ws + 42991616);
  u16*   Qb    = (u16*)(ws + 42991616);
  u16*   Wob   = (u16*)(ws + 59768832);
  u16*   Wkvb  = (u16*)(ws + 68157440);
  u16*   Wrkb  = (u16*)(ws + 70254592);
  u16*   Wqb   = (u16*)(ws + 70516736);
  u16*   Kb    = (u16*)(ws + 70516736);
  u16*   VTb   = (u16*)(ws + 74711040);

  // 1) casts to bf16
  cast_bf16_kernel<<<(MM * DD / 4) / 256, 256, 0, stream>>>(x, xb, MM * DD / 4);
  cast_bf16_kernel<<<(HH * HDD * DD / 4) / 256, 256, 0, stream>>>(Wq, Wqb, HH * HDD * DD / 4);
  cast_bf16_kernel<<<(KVH * HDD * DD / 4) / 256, 256, 0, stream>>>(Wkv, Wkvb, KVH * HDD * DD / 4);
  cast_bf16_kernel<<<(RDD * DD / 4) / 256, 256, 0, stream>>>(Wrk, Wrkb, RDD * DD / 4);
  cast_bf16_kernel<<<(DD * HH * HDD / 4) / 256, 256, 0, stream>>>(Wo, Wob, DD * HH * HDD / 4);

  // 2) input projections (f32 out)
  gemm128<<<dim3(DD / 128, MM / 128), 256, 0, stream>>>(xb, Wqb, bq, qbuf, MM, DD, DD);
  gemm128<<<dim3((KVH * HDD) / 128, MM / 128), 256, 0, stream>>>(xb, Wkvb, bkv, kvbuf, MM, KVH * HDD, DD);
  gemm_bf16_nt<<<dim3(RDD / 16, MM / 16), 64, 0, stream>>>(xb, Wrkb, brk, krbuf, MM, RDD, DD);

  // 3) build bf16 attention operands (rope folded in)
  build_k_kernel<<<(BB * KVH * LL * HDD) / 256, 256, 0, stream>>>(kvbuf, krbuf, cosb, sinb, Kb);
  build_vt_kernel<<<dim3(LL / 32, HDD / 32, BB * KVH), 256, 0, stream>>>(kvbuf, VTb);
  build_q_kernel<<<(MM * HH * HDD) / 256, 256, 0, stream>>>(qbuf, cosb, sinb, Qb);

  // 4) MFMA flash attention v3 -> bf16
  attn_mfma3<<<dim3(512), 256, 0, stream>>>(Qb, Kb, VTb, attn_bf);

  // 5) output projection -> d_out (f32)
  gemm128<<<dim3(DD / 128, MM / 128), 256, 0, stream>>>(attn_bf, Wob, bo, out, MM, DD, DD);
}